// Round 9
// baseline (839.894 us; speedup 1.0000x reference)
//
#include <hip/hip_runtime.h>
#include <hip/hip_cooperative_groups.h>
#include <hip/hip_bf16.h>

namespace cg = cooperative_groups;

// DigitCaps dynamic routing. Output fp32.
// R9: single cooperative kernel (grid.sync between phases). R8 showed the
// total is dispatch-count-bound (14 launches, ~15us/slot; per-kernel fixes
// moved nothing). Numeric path identical to R8 (bf16 MFMA s-GEMM, absmax
// 4.9e-4). d_ws measured ~268MB via harness fill — no aliasing needed.
#define B 512
#define IC 1152
#define QD 8
#define OD 10
#define PD 16
#define KD (IC * QD)       // 9216
#define NKB (KD / 32)      // 288 K32 blocks
#define NCS 36             // K-chunks for s GEMM; 288/36 = 8 K-steps
#define KSTEPS (NKB / NCS)
#define NCB 16             // b-chunks for agreement
#define CSB (B / NCB)      // 32
#define SOP (B * OD * PD)  // 81920
#define SUNITS (8 * 2 * NCS)  // 576 sgemm block-units
#define AUNITS (144 * NCB)    // 2304 agree wave-units

typedef short bf16x8 __attribute__((ext_vector_type(8)));
typedef float f32x4 __attribute__((ext_vector_type(4)));

__device__ __forceinline__ short f2bf(float f) {
  union { float f; unsigned u; } x;
  x.f = f;
  unsigned r = x.u + 0x7FFFu + ((x.u >> 16) & 1u);  // RNE to bf16
  return (short)(r >> 16);
}

// ---------------- device phase helpers (shared by fused + fallback) ---------

__device__ __forceinline__ void phase_build_b(const float* __restrict__ W,
                                              const float* __restrict__ c,
                                              short* __restrict__ Bs,
                                              int uniform_c, int gtid, int nthreads) {
  for (int t = gtid; t < NKB * 160; t += nthreads) {
    const int kb = t / 160, n = t % 160;
    const int o = n >> 4, p = n & 15;
    short ov[32];
#pragma unroll
    for (int quad = 0; quad < 4; ++quad) {
      const int i = kb * 4 + quad;
      const float ci = uniform_c ? (1.0f / (float)IC) : c[i * OD + o];
      const float4* wp = (const float4*)(W + (((size_t)i * OD + o) * PD + p) * QD);
      const float4 w0 = wp[0], w1 = wp[1];
      ov[quad * 8 + 0] = f2bf(ci * w0.x);
      ov[quad * 8 + 1] = f2bf(ci * w0.y);
      ov[quad * 8 + 2] = f2bf(ci * w0.z);
      ov[quad * 8 + 3] = f2bf(ci * w0.w);
      ov[quad * 8 + 4] = f2bf(ci * w1.x);
      ov[quad * 8 + 5] = f2bf(ci * w1.y);
      ov[quad * 8 + 6] = f2bf(ci * w1.z);
      ov[quad * 8 + 7] = f2bf(ci * w1.w);
    }
    int4* dst = (int4*)(Bs + (size_t)t * 32);
    const int4* src = (const int4*)ov;
#pragma unroll
    for (int j = 0; j < 4; ++j) dst[j] = src[j];
  }
}

__device__ __forceinline__ void phase_sgemm_unit(const float* __restrict__ x,
                                                 const short* __restrict__ Bs,
                                                 float* __restrict__ s_part,
                                                 int unit, int wave, int lane) {
  const int cz = unit % NCS;
  const int mn = unit / NCS;          // 0..15
  const int mb = mn >> 1, nh = mn & 1;
  const int ln = lane & 15, quad = lane >> 4;
  const int m0 = mb * 64 + wave * 16;
  const int nb = nh * 80;
  f32x4 acc[5] = {};
  const float* arow = x + (size_t)(m0 + ln) * KD + quad * 8;
#pragma unroll 2
  for (int step = 0; step < KSTEPS; ++step) {
    const int kb = cz * KSTEPS + step;
    const float* ap = arow + kb * 32;
    const f32x4 a0 = *(const f32x4*)ap;
    const f32x4 a1 = *(const f32x4*)(ap + 4);
    bf16x8 af;
    af[0] = f2bf(a0[0]); af[1] = f2bf(a0[1]); af[2] = f2bf(a0[2]); af[3] = f2bf(a0[3]);
    af[4] = f2bf(a1[0]); af[5] = f2bf(a1[1]); af[6] = f2bf(a1[2]); af[7] = f2bf(a1[3]);
    const short* bp = Bs + (size_t)kb * 5120 + (nb + ln) * 32 + quad * 8;
#pragma unroll
    for (int nt = 0; nt < 5; ++nt) {
      const bf16x8 bf = *(const bf16x8*)(bp + nt * 512);
      acc[nt] = __builtin_amdgcn_mfma_f32_16x16x32_bf16(af, bf, acc[nt], 0, 0, 0);
    }
  }
  // C/D layout: col = lane&15, row = quad*4 + reg  [m89-verified]
  float* sp = s_part + (size_t)cz * SOP;
#pragma unroll
  for (int nt = 0; nt < 5; ++nt) {
#pragma unroll
    for (int r = 0; r < 4; ++r) {
      sp[(size_t)(m0 + quad * 4 + r) * 160 + nb + nt * 16 + ln] = acc[nt][r];
    }
  }
}

__device__ __forceinline__ void phase_squash(const float* __restrict__ s_part,
                                             float* __restrict__ v,
                                             float* __restrict__ out,
                                             int write_out, int gtid, int nthreads) {
  for (int t = gtid; t < SOP; t += nthreads) {  // SOP % 64 == 0: waves stay aligned
    float sv = 0.f;
#pragma unroll
    for (int ch = 0; ch < NCS; ++ch) sv += s_part[(size_t)ch * SOP + t];
    float sq = sv * sv;
#pragma unroll
    for (int m = 1; m < 16; m <<= 1) sq += __shfl_xor(sq, m, 16);
    const float norm = sqrtf(sq + 1e-8f);
    const float val = sv * (sq / ((1.f + sq) * norm));
    v[t] = val;
    if (write_out) out[t] = val;
  }
}

__device__ __forceinline__ void phase_agree_unit(const float* __restrict__ x,
                                                 const float* __restrict__ W,
                                                 const float* __restrict__ v,
                                                 float* __restrict__ u_part,
                                                 int wu, int lane) {
  const int ig = wu >> 4, bc = wu & 15;
  const int il = lane >> 3, q = lane & 7;
  const int i = ig * 8 + il;
  const int b0 = bc * CSB;
  for (int opair = 0; opair < 5; ++opair) {
    const int o1 = opair, o2 = opair + 5;
    float G0[PD], G1[PD];
#pragma unroll
    for (int p = 0; p < PD; ++p) { G0[p] = 0.f; G1[p] = 0.f; }
    for (int b = b0; b < b0 + CSB; ++b) {
      const float xa = x[((size_t)b * IC + i) * QD + q];  // coalesced 256B/wave
      const int vo0 = __builtin_amdgcn_readfirstlane((b * OD + o1) * PD);
      const int vo1 = __builtin_amdgcn_readfirstlane((b * OD + o2) * PD);
      const float4* vp0 = (const float4*)(v + vo0);
      const float4* vp1 = (const float4*)(v + vo1);
      const float4 a0 = vp0[0], a1 = vp0[1], a2 = vp0[2], a3 = vp0[3];
      const float4 c0 = vp1[0], c1 = vp1[1], c2 = vp1[2], c3 = vp1[3];
      const float va[PD] = {a0.x, a0.y, a0.z, a0.w, a1.x, a1.y, a1.z, a1.w,
                            a2.x, a2.y, a2.z, a2.w, a3.x, a3.y, a3.z, a3.w};
      const float vc[PD] = {c0.x, c0.y, c0.z, c0.w, c1.x, c1.y, c1.z, c1.w,
                            c2.x, c2.y, c2.z, c2.w, c3.x, c3.y, c3.z, c3.w};
#pragma unroll
      for (int p = 0; p < PD; ++p) G0[p] = fmaf(xa, va[p], G0[p]);
#pragma unroll
      for (int p = 0; p < PD; ++p) G1[p] = fmaf(xa, vc[p], G1[p]);
    }
    const float* wq1 = W + ((size_t)(i * OD + o1) * PD) * QD + q;
    const float* wq2 = W + ((size_t)(i * OD + o2) * PD) * QD + q;
    float u0 = 0.f, u1 = 0.f;
#pragma unroll
    for (int p = 0; p < PD; ++p) {
      u0 = fmaf(wq1[(size_t)p * QD], G0[p], u0);
      u1 = fmaf(wq2[(size_t)p * QD], G1[p], u1);
    }
    u0 += __shfl_xor(u0, 1); u0 += __shfl_xor(u0, 2); u0 += __shfl_xor(u0, 4);
    u1 += __shfl_xor(u1, 1); u1 += __shfl_xor(u1, 2); u1 += __shfl_xor(u1, 4);
    if (q == 0) {
      float* up = u_part + ((size_t)bc * IC + i) * OD;
      up[o1] = u0 * (1.0f / (float)B);
      up[o2] = u1 * (1.0f / (float)B);
    }
  }
}

__device__ __forceinline__ void phase_route_o(const float* __restrict__ u_part,
                                              float* __restrict__ bij,
                                              float* __restrict__ c,
                                              int add_prev, int o, float* red, int tx) {
  float val[5];
  float lmax = -1e30f;
#pragma unroll
  for (int k = 0; k < 5; ++k) {
    const int i = tx + k * 256;
    if (i < IC) {
      float sacc = add_prev ? bij[i * OD + o] : 0.f;
#pragma unroll
      for (int ch = 0; ch < NCB; ++ch) sacc += u_part[((size_t)ch * IC + i) * OD + o];
      val[k] = sacc;
      bij[i * OD + o] = sacc;
      lmax = fmaxf(lmax, sacc);
    } else {
      val[k] = -1e30f;
    }
  }
  red[tx] = lmax;
  __syncthreads();
  for (int st = 128; st > 0; st >>= 1) {
    if (tx < st) red[tx] = fmaxf(red[tx], red[tx + st]);
    __syncthreads();
  }
  const float gmax = red[0];
  __syncthreads();
  float lsum = 0.f;
#pragma unroll
  for (int k = 0; k < 5; ++k) {
    const int i = tx + k * 256;
    if (i < IC) {
      val[k] = __expf(val[k] - gmax);
      lsum += val[k];
    }
  }
  red[tx] = lsum;
  __syncthreads();
  for (int st = 128; st > 0; st >>= 1) {
    if (tx < st) red[tx] += red[tx + st];
    __syncthreads();
  }
  const float inv = 1.f / red[0];
  __syncthreads();
#pragma unroll
  for (int k = 0; k < 5; ++k) {
    const int i = tx + k * 256;
    if (i < IC) c[i * OD + o] = val[k] * inv;
  }
}

// ---------------- fused cooperative kernel ----------------------------------

__global__ __launch_bounds__(256) void fused_kernel(const float* __restrict__ x,
                                                    const float* __restrict__ W,
                                                    float* __restrict__ out,
                                                    float* __restrict__ s_part,
                                                    float* __restrict__ v,
                                                    float* __restrict__ bij,
                                                    float* __restrict__ c,
                                                    short* __restrict__ Bs,
                                                    float* __restrict__ u_part) {
  cg::grid_group grid = cg::this_grid();
  __shared__ float red[256];
  const int tx = threadIdx.x;
  const int wave = tx >> 6, lane = tx & 63;
  const int nthreads = gridDim.x * 256;
  const int gtid = blockIdx.x * 256 + tx;
  const int nwaves = gridDim.x * 4;
  const int gwave = blockIdx.x * 4 + wave;

  for (int iter = 0; iter < 3; ++iter) {
    phase_build_b(W, c, Bs, iter == 0, gtid, nthreads);
    grid.sync();
    for (int u = blockIdx.x; u < SUNITS; u += gridDim.x)
      phase_sgemm_unit(x, Bs, s_part, u, wave, lane);
    grid.sync();
    phase_squash(s_part, v, out, iter == 2, gtid, nthreads);
    if (iter == 2) break;
    grid.sync();
    for (int wu = gwave; wu < AUNITS; wu += nwaves)
      phase_agree_unit(x, W, v, u_part, wu, lane);
    grid.sync();
    for (int o = blockIdx.x; o < OD; o += gridDim.x)
      phase_route_o(u_part, bij, c, iter > 0, o, red, tx);
    grid.sync();
  }
}

// ---------------- standalone fallback kernels (R8 path) ---------------------

__global__ __launch_bounds__(256) void build_b_kernel(const float* __restrict__ W,
                                                      const float* __restrict__ c,
                                                      short* __restrict__ Bs,
                                                      int uniform_c) {
  phase_build_b(W, c, Bs, uniform_c, blockIdx.x * 256 + threadIdx.x, gridDim.x * 256);
}

__global__ __launch_bounds__(256) void sgemm_kernel(const float* __restrict__ x,
                                                    const short* __restrict__ Bs,
                                                    float* __restrict__ s_part) {
  for (int u = blockIdx.x; u < SUNITS; u += gridDim.x)
    phase_sgemm_unit(x, Bs, s_part, u, threadIdx.x >> 6, threadIdx.x & 63);
}

__global__ __launch_bounds__(256) void squash_kernel(const float* __restrict__ s_part,
                                                     float* __restrict__ v,
                                                     float* __restrict__ out,
                                                     int write_out) {
  phase_squash(s_part, v, out, write_out, blockIdx.x * 256 + threadIdx.x, gridDim.x * 256);
}

__global__ __launch_bounds__(256) void agree_kernel(const float* __restrict__ x,
                                                    const float* __restrict__ W,
                                                    const float* __restrict__ v,
                                                    float* __restrict__ u_part) {
  const int wave = threadIdx.x >> 6, lane = threadIdx.x & 63;
  for (int wu = blockIdx.x * 4 + wave; wu < AUNITS; wu += gridDim.x * 4)
    phase_agree_unit(x, W, v, u_part, wu, lane);
}

__global__ __launch_bounds__(256) void route_kernel(const float* __restrict__ u_part,
                                                    float* __restrict__ bij,
                                                    float* __restrict__ c,
                                                    int add_prev) {
  __shared__ float red[256];
  for (int o = blockIdx.x; o < OD; o += gridDim.x)
    phase_route_o(u_part, bij, c, add_prev, o, red, threadIdx.x);
}

// ---------------- launch ----------------------------------------------------

extern "C" void kernel_launch(void* const* d_in, const int* in_sizes, int n_in,
                              void* d_out, int out_size, void* d_ws, size_t ws_size,
                              hipStream_t stream) {
  const float* x = (const float*)d_in[0];  // [512,1152,8] fp32
  const float* W = (const float*)d_in[1];  // [1152,10,16,8] fp32
  float* out = (float*)d_out;              // [512,10,16] fp32

  // workspace (~16 MB of the ~268 MB d_ws), no aliasing
  float* ws = (float*)d_ws;
  float* s_part = ws;                          // 36*81920 = 2,949,120 floats
  float* v = s_part + (size_t)NCS * SOP;       // 81920
  float* bij = v + SOP;                        // 11520
  float* c = bij + IC * OD;                    // 11520
  float* u_part = c + IC * OD;                 // 16*1152*10 = 184,320
  short* Bs = (short*)(u_part + (size_t)NCB * IC * OD);  // 288*160*32 shorts

  // cooperative grid: clamp to occupancy (deterministic host-side query)
  int maxb = 0;
  hipError_t oe = hipOccupancyMaxActiveBlocksPerMultiprocessor(&maxb, (const void*)fused_kernel, 256, 0);
  int grid = SUNITS;  // 576
  if (oe == hipSuccess && maxb >= 1) {
    const int cap = maxb * 256;  // 256 CUs
    if (grid > cap) grid = cap;
  }

  void* args[] = {(void*)&x, (void*)&W, (void*)&out, (void*)&s_part, (void*)&v,
                  (void*)&bij, (void*)&c, (void*)&Bs, (void*)&u_part};
  hipError_t e = hipLaunchCooperativeKernel((const void*)fused_kernel, dim3(grid), dim3(256),
                                            args, 0, stream);
  if (e != hipSuccess) {
    // deterministic fallback: R8 multi-launch path
    (void)hipGetLastError();  // clear
    for (int iter = 0; iter < 3; ++iter) {
      build_b_kernel<<<180, 256, 0, stream>>>(W, c, Bs, iter == 0);
      sgemm_kernel<<<SUNITS, 256, 0, stream>>>(x, Bs, s_part);
      squash_kernel<<<SOP / 256, 256, 0, stream>>>(s_part, v, out, iter == 2);
      if (iter < 2) {
        agree_kernel<<<AUNITS / 4, 256, 0, stream>>>(x, W, v, u_part);
        route_kernel<<<OD, 256, 0, stream>>>(u_part, bij, c, iter > 0);
      }
    }
  }
}

// Round 10
// 226.309 us; speedup vs baseline: 3.7113x; 3.7113x over previous
//
#include <hip/hip_runtime.h>
#include <hip/hip_bf16.h>

// DigitCaps dynamic routing. Output fp32.
// R10: single cooperative kernel with CUSTOM 2-level tree barrier.
// R9 evidence: phase work ~75us, cg::grid.sync ~87us x12 = the 1118us dispatch.
// Tree barrier (32 leaves -> root -> gen flip, agent-scope atomics, device-
// global state untouched by ws poison) should be ~3-5us/sync, 10 syncs.
// build_b folded into sgemm (B-tile in LDS, c=softmax inline from bij+stats);
// agree stages x in LDS (kills 5x redundant x reads). Fallback: 10 launches.
#define B 512
#define IC 1152
#define QD 8
#define OD 10
#define PD 16
#define KD (IC * QD)       // 9216
#define NKB (KD / 32)      // 288 K32 blocks
#define NCS 72             // K-chunks for s GEMM; 288/72 = 4 K-steps
#define KSTEPS (NKB / NCS)
#define NCB 16             // b-chunks for agreement
#define CSB (B / NCB)      // 32
#define SOP (B * OD * PD)  // 81920
#define SUNITS 576         // sgemm units (8 m-blocks x 72 cz) == agree units (144 ig x 4 bq)

typedef short bf16x8 __attribute__((ext_vector_type(8)));
typedef float f32x4 __attribute__((ext_vector_type(4)));

__device__ __forceinline__ short f2bf(float f) {
  union { float f; unsigned u; } x;
  x.f = f;
  unsigned r = x.u + 0x7FFFu + ((x.u >> 16) & 1u);  // RNE to bf16
  return (short)(r >> 16);
}

// ---------------- tree barrier (device-global state, self-resetting) --------
__device__ int g_leaf[32];
__device__ int g_root;
__device__ unsigned g_gen;

__device__ __forceinline__ void gsync(int nblk) {
  __syncthreads();
  if (threadIdx.x == 0) {
    __threadfence();
    const int lid = blockIdx.x & 31;
    const int leafcnt = (nblk >> 5) + ((lid < (nblk & 31)) ? 1 : 0);
    const unsigned g = __hip_atomic_load(&g_gen, __ATOMIC_RELAXED, __HIP_MEMORY_SCOPE_AGENT);
    const int lv = __hip_atomic_fetch_add(&g_leaf[lid], 1, __ATOMIC_ACQ_REL, __HIP_MEMORY_SCOPE_AGENT);
    if (lv == leafcnt - 1) {
      __hip_atomic_store(&g_leaf[lid], 0, __ATOMIC_RELAXED, __HIP_MEMORY_SCOPE_AGENT);
      const int nleaf = (nblk < 32) ? nblk : 32;
      const int rv = __hip_atomic_fetch_add(&g_root, 1, __ATOMIC_ACQ_REL, __HIP_MEMORY_SCOPE_AGENT);
      if (rv == nleaf - 1) {
        __hip_atomic_store(&g_root, 0, __ATOMIC_RELAXED, __HIP_MEMORY_SCOPE_AGENT);
        __hip_atomic_fetch_add(&g_gen, 1u, __ATOMIC_RELEASE, __HIP_MEMORY_SCOPE_AGENT);
      }
    }
    while (__hip_atomic_load(&g_gen, __ATOMIC_ACQUIRE, __HIP_MEMORY_SCOPE_AGENT) == g) {
      __builtin_amdgcn_s_sleep(2);
    }
    __threadfence();
  }
  __syncthreads();
}

// ---------------- phases ----------------------------------------------------

// s_part[cz][b][n] partial GEMM with B-tile built in LDS from W and inline
// softmax c[i,o] = exp(bij - mx[o]) * inv[o] (uniform 1/IC when uniform=1).
// unit u: mb = u/NCS (m-block of 64 rows), cz = u%NCS (K-chunk of KSTEPS kb).
__device__ __forceinline__ void phase_sgemm(const float* __restrict__ x,
                                            const float* __restrict__ W,
                                            const float* __restrict__ bij,
                                            const float* __restrict__ stats,
                                            int uniform, float* __restrict__ s_part,
                                            short* bls, int blk, int nblk, int tid) {
  const int wave = tid >> 6, lane = tid & 63;
  const int ln = lane & 15, qd4 = lane >> 4;
  for (int u = blk; u < SUNITS; u += nblk) {
    const int mb = u / NCS, cz = u % NCS;
    const int m0 = mb * 64 + wave * 16;
    f32x4 acc[10] = {};
    for (int s = 0; s < KSTEPS; ++s) {
      const int kb = cz * KSTEPS + s;
      __syncthreads();
      // build 1 kb: 160 n x 4 quad entries of 8 bf16 each, row stride 40 shorts
      for (int e = tid; e < 640; e += 256) {
        const int n = e >> 2, bq = e & 3;
        const int i = kb * 4 + bq, o = n >> 4, p = n & 15;
        float ci;
        if (uniform) ci = 1.0f / (float)IC;
        else ci = __expf(bij[i * OD + o] - stats[2 * o]) * stats[2 * o + 1];
        const float4* wp = (const float4*)(W + (((size_t)i * OD + o) * PD + p) * QD);
        const float4 w0 = wp[0], w1 = wp[1];
        short* d = bls + n * 40 + bq * 8;
        d[0] = f2bf(ci * w0.x); d[1] = f2bf(ci * w0.y);
        d[2] = f2bf(ci * w0.z); d[3] = f2bf(ci * w0.w);
        d[4] = f2bf(ci * w1.x); d[5] = f2bf(ci * w1.y);
        d[6] = f2bf(ci * w1.z); d[7] = f2bf(ci * w1.w);
      }
      __syncthreads();
      const float* ap = x + (size_t)(m0 + ln) * KD + kb * 32 + qd4 * 8;
      const f32x4 a0 = *(const f32x4*)ap;
      const f32x4 a1 = *(const f32x4*)(ap + 4);
      bf16x8 af;
      af[0] = f2bf(a0[0]); af[1] = f2bf(a0[1]); af[2] = f2bf(a0[2]); af[3] = f2bf(a0[3]);
      af[4] = f2bf(a1[0]); af[5] = f2bf(a1[1]); af[6] = f2bf(a1[2]); af[7] = f2bf(a1[3]);
#pragma unroll
      for (int nt = 0; nt < 10; ++nt) {
        const bf16x8 bf = *(const bf16x8*)(bls + (nt * 16 + ln) * 40 + qd4 * 8);
        acc[nt] = __builtin_amdgcn_mfma_f32_16x16x32_bf16(af, bf, acc[nt], 0, 0, 0);
      }
    }
    // C/D layout: col = lane&15, row = quad*4 + reg  [m89-verified]
    float* sp = s_part + (size_t)cz * SOP;
#pragma unroll
    for (int nt = 0; nt < 10; ++nt)
#pragma unroll
      for (int r = 0; r < 4; ++r)
        sp[(size_t)(m0 + qd4 * 4 + r) * 160 + nt * 16 + ln] = acc[nt][r];
  }
}

__device__ __forceinline__ void phase_squash(const float* __restrict__ s_part,
                                             float* __restrict__ v,
                                             float* __restrict__ out,
                                             int write_out, int gtid, int nthreads) {
  for (int t = gtid; t < SOP; t += nthreads) {
    float sv = 0.f;
#pragma unroll 8
    for (int ch = 0; ch < NCS; ++ch) sv += s_part[(size_t)ch * SOP + t];
    float sq = sv * sv;
#pragma unroll
    for (int m = 1; m < 16; m <<= 1) sq += __shfl_xor(sq, m, 16);
    const float norm = sqrtf(sq + 1e-8f);
    const float val = sv * (sq / ((1.f + sq) * norm));
    v[t] = val;
    if (write_out) out[t] = val;
  }
}

// u_part[bc][i][o]: unit u0 = ig*4 + bquad; block stages x[bbase..+128)[ig*8..+8)[:]
// into LDS once; 4 waves handle 4 b-chunks of 32; 5 o-pairs reuse the tile.
__device__ __forceinline__ void phase_agree(const float* __restrict__ x,
                                            const float* __restrict__ W,
                                            const float* __restrict__ v,
                                            float* __restrict__ u_part,
                                            float* xs, int blk, int nblk, int tid) {
  const int wave = tid >> 6, lane = tid & 63;
  const int il = lane >> 3, q = lane & 7;
  for (int u0 = blk; u0 < SUNITS; u0 += nblk) {
    const int ig = u0 >> 2, bquad = u0 & 3;
    const int bbase = bquad * 128;
    const int i = ig * 8 + il;
    __syncthreads();
    for (int idx = tid; idx < 2048; idx += 256) {
      const int row = idx >> 4, f4 = idx & 15;
      *(float4*)(xs + row * 64 + f4 * 4) =
          *(const float4*)(x + (size_t)(bbase + row) * KD + ig * 64 + f4 * 4);
    }
    __syncthreads();
    const int bc = bquad * 4 + wave;
    const int b0 = bc * CSB;
    const float* xw = xs + wave * 32 * 64 + il * 8 + q;
#pragma unroll
    for (int opair = 0; opair < 5; ++opair) {
      const int o1 = opair, o2 = opair + 5;
      float G0[PD], G1[PD];
#pragma unroll
      for (int p = 0; p < PD; ++p) { G0[p] = 0.f; G1[p] = 0.f; }
      for (int b = 0; b < CSB; ++b) {
        const float xa = xw[b * 64];  // LDS, bank-free (2-way)
        const int vo0 = __builtin_amdgcn_readfirstlane(((b0 + b) * OD + o1) * PD);
        const int vo1 = __builtin_amdgcn_readfirstlane(((b0 + b) * OD + o2) * PD);
        const float4* vp0 = (const float4*)(v + vo0);
        const float4* vp1 = (const float4*)(v + vo1);
        const float4 a0 = vp0[0], a1 = vp0[1], a2 = vp0[2], a3 = vp0[3];
        const float4 c0 = vp1[0], c1 = vp1[1], c2 = vp1[2], c3 = vp1[3];
        const float va[PD] = {a0.x, a0.y, a0.z, a0.w, a1.x, a1.y, a1.z, a1.w,
                              a2.x, a2.y, a2.z, a2.w, a3.x, a3.y, a3.z, a3.w};
        const float vc[PD] = {c0.x, c0.y, c0.z, c0.w, c1.x, c1.y, c1.z, c1.w,
                              c2.x, c2.y, c2.z, c2.w, c3.x, c3.y, c3.z, c3.w};
#pragma unroll
        for (int p = 0; p < PD; ++p) G0[p] = fmaf(xa, va[p], G0[p]);
#pragma unroll
        for (int p = 0; p < PD; ++p) G1[p] = fmaf(xa, vc[p], G1[p]);
      }
      const float* wq1 = W + ((size_t)(i * OD + o1) * PD) * QD + q;
      const float* wq2 = W + ((size_t)(i * OD + o2) * PD) * QD + q;
      float u0s = 0.f, u1s = 0.f;
#pragma unroll
      for (int p = 0; p < PD; ++p) {
        u0s = fmaf(wq1[(size_t)p * QD], G0[p], u0s);
        u1s = fmaf(wq2[(size_t)p * QD], G1[p], u1s);
      }
      u0s += __shfl_xor(u0s, 1); u0s += __shfl_xor(u0s, 2); u0s += __shfl_xor(u0s, 4);
      u1s += __shfl_xor(u1s, 1); u1s += __shfl_xor(u1s, 2); u1s += __shfl_xor(u1s, 4);
      if (q == 0) {
        float* up = u_part + ((size_t)bc * IC + i) * OD;
        up[o1] = u0s * (1.0f / (float)B);
        up[o2] = u1s * (1.0f / (float)B);
      }
    }
  }
}

// bij += sum_chunk u_part; stats[o] = (max_i bij, 1/sum_i exp(bij-max)).
__device__ __forceinline__ void phase_route(const float* __restrict__ u_part,
                                            float* __restrict__ bij,
                                            float* __restrict__ stats,
                                            int add_prev, float* red, int blk, int nblk, int tid) {
  for (int o = blk; o < OD; o += nblk) {
    __syncthreads();
    float val[5];
    float lmax = -1e30f;
#pragma unroll
    for (int k = 0; k < 5; ++k) {
      const int i = tid + k * 256;
      if (i < IC) {
        float sacc = add_prev ? bij[i * OD + o] : 0.f;
#pragma unroll
        for (int ch = 0; ch < NCB; ++ch) sacc += u_part[((size_t)ch * IC + i) * OD + o];
        val[k] = sacc;
        bij[i * OD + o] = sacc;
        lmax = fmaxf(lmax, sacc);
      } else {
        val[k] = -1e30f;
      }
    }
    red[tid] = lmax;
    __syncthreads();
    for (int st = 128; st > 0; st >>= 1) {
      if (tid < st) red[tid] = fmaxf(red[tid], red[tid + st]);
      __syncthreads();
    }
    const float gmax = red[0];
    __syncthreads();
    float lsum = 0.f;
#pragma unroll
    for (int k = 0; k < 5; ++k) {
      const int i = tid + k * 256;
      if (i < IC) lsum += __expf(val[k] - gmax);
    }
    red[tid] = lsum;
    __syncthreads();
    for (int st = 128; st > 0; st >>= 1) {
      if (tid < st) red[tid] += red[tid + st];
      __syncthreads();
    }
    if (tid == 0) {
      stats[2 * o] = gmax;
      stats[2 * o + 1] = 1.f / red[0];
    }
    __syncthreads();
  }
}

// ---------------- fused cooperative kernel ----------------------------------

__global__ __launch_bounds__(256) void fused_kernel(const float* __restrict__ x,
                                                    const float* __restrict__ W,
                                                    float* __restrict__ out,
                                                    float* __restrict__ s_part,
                                                    float* __restrict__ v,
                                                    float* __restrict__ bij,
                                                    float* __restrict__ stats,
                                                    float* __restrict__ u_part) {
  __shared__ __align__(16) char smem[32768];  // union: bls 12.8KB / xs 32KB / red 1KB
  short* bls = (short*)smem;
  float* xs = (float*)smem;
  float* red = (float*)smem;
  const int tid = threadIdx.x;
  const int nblk = gridDim.x, blk = blockIdx.x;
  const int gtid = blk * 256 + tid, nthreads = nblk * 256;

  for (int iter = 0; iter < 3; ++iter) {
    phase_sgemm(x, W, bij, stats, iter == 0, s_part, bls, blk, nblk, tid);
    gsync(nblk);
    phase_squash(s_part, v, out, iter == 2, gtid, nthreads);
    if (iter == 2) break;
    gsync(nblk);
    phase_agree(x, W, v, u_part, xs, blk, nblk, tid);
    gsync(nblk);
    phase_route(u_part, bij, stats, iter > 0, red, blk, nblk, tid);
    gsync(nblk);
  }
}

// ---------------- standalone fallback kernels -------------------------------

__global__ __launch_bounds__(256) void sgemm_kernel(const float* __restrict__ x,
                                                    const float* __restrict__ W,
                                                    const float* __restrict__ bij,
                                                    const float* __restrict__ stats,
                                                    int uniform,
                                                    float* __restrict__ s_part) {
  __shared__ __align__(16) short bls[160 * 40];
  phase_sgemm(x, W, bij, stats, uniform, s_part, bls, blockIdx.x, gridDim.x, threadIdx.x);
}

__global__ __launch_bounds__(256) void squash_kernel(const float* __restrict__ s_part,
                                                     float* __restrict__ v,
                                                     float* __restrict__ out,
                                                     int write_out) {
  phase_squash(s_part, v, out, write_out, blockIdx.x * 256 + threadIdx.x, gridDim.x * 256);
}

__global__ __launch_bounds__(256) void agree_kernel(const float* __restrict__ x,
                                                    const float* __restrict__ W,
                                                    const float* __restrict__ v,
                                                    float* __restrict__ u_part) {
  __shared__ __align__(16) float xs[128 * 64];
  phase_agree(x, W, v, u_part, xs, blockIdx.x, gridDim.x, threadIdx.x);
}

__global__ __launch_bounds__(256) void route_kernel(const float* __restrict__ u_part,
                                                    float* __restrict__ bij,
                                                    float* __restrict__ stats,
                                                    int add_prev) {
  __shared__ float red[256];
  phase_route(u_part, bij, stats, add_prev, red, blockIdx.x, gridDim.x, threadIdx.x);
}

// ---------------- launch ----------------------------------------------------

extern "C" void kernel_launch(void* const* d_in, const int* in_sizes, int n_in,
                              void* d_out, int out_size, void* d_ws, size_t ws_size,
                              hipStream_t stream) {
  const float* x = (const float*)d_in[0];  // [512,1152,8] fp32
  const float* W = (const float*)d_in[1];  // [1152,10,16,8] fp32
  float* out = (float*)d_out;              // [512,10,16] fp32

  // workspace ~24.7 MB of ~268 MB d_ws; everything written before read each call
  float* ws = (float*)d_ws;
  float* s_part = ws;                          // 72*81920 = 5,898,240 floats
  float* v = s_part + (size_t)NCS * SOP;       // 81920
  float* bij = v + SOP;                        // 11520
  float* stats = bij + IC * OD;                // 20
  float* u_part = stats + 32;                  // 16*11520 = 184,320

  int maxb = 0;
  hipError_t oe = hipOccupancyMaxActiveBlocksPerMultiprocessor(&maxb, (const void*)fused_kernel, 256, 0);
  bool coop = (oe == hipSuccess) && (maxb * 256 >= SUNITS);
  if (coop) {
    void* args[] = {(void*)&x, (void*)&W, (void*)&out, (void*)&s_part, (void*)&v,
                    (void*)&bij, (void*)&stats, (void*)&u_part};
    hipError_t e = hipLaunchCooperativeKernel((const void*)fused_kernel, dim3(SUNITS), dim3(256),
                                              args, 0, stream);
    if (e != hipSuccess) { (void)hipGetLastError(); coop = false; }
  }
  if (!coop) {
    for (int iter = 0; iter < 3; ++iter) {
      sgemm_kernel<<<SUNITS, 256, 0, stream>>>(x, W, bij, stats, iter == 0, s_part);
      squash_kernel<<<SOP / 256, 256, 0, stream>>>(s_part, v, out, iter == 2);
      if (iter < 2) {
        agree_kernel<<<SUNITS, 256, 0, stream>>>(x, W, v, u_part);
        route_kernel<<<OD, 256, 0, stream>>>(u_part, bij, stats, iter > 0);
      }
    }
  }
}